// Round 4
// baseline (538.115 us; speedup 1.0000x reference)
//
#include <hip/hip_runtime.h>
#include <math.h>

#define EMBED 1024
#define HEADS 16
#define HD    64
#define NB    4
#define LSEQ  2048

typedef __attribute__((ext_vector_type(8))) short bf16x8;
typedef __attribute__((ext_vector_type(16))) float f32x16;

typedef __attribute__((address_space(1))) void as1_void;
typedef __attribute__((address_space(3))) void as3_void;

__device__ __forceinline__ void gload_lds16(const void* g, void* l) {
    __builtin_amdgcn_global_load_lds((const as1_void*)g, (as3_void*)l, 16, 0, 0);
}

__device__ inline bf16x8 as_bf16x8(uint4 u) {
    union { uint4 u; bf16x8 b; } c; c.u = u; return c.b;
}
// round-to-nearest-even fp32 -> bf16 (raw ushort); finite inputs only
__device__ inline unsigned short bf16r(float x) {
    unsigned u = __float_as_uint(x);
    u += 0x7fffu + ((u >> 16) & 1u);
    return (unsigned short)(u >> 16);
}
__device__ inline float bfh2f(unsigned short h) {
    return __uint_as_float(((unsigned)h) << 16);
}

// ---------------------------------------------------------------------------
// Kernel 1: per-head QKV projections -> bf16 (unchanged from R3).
// ---------------------------------------------------------------------------
__global__ __launch_bounds__(256) void proj_kernel(
    const float* __restrict__ Xv, const float* __restrict__ Xk, const float* __restrict__ Xq,
    const float* __restrict__ Wv, const float* __restrict__ Wk, const float* __restrict__ Wq,
    unsigned short* __restrict__ Vt, unsigned short* __restrict__ Kp, unsigned short* __restrict__ Qp)
{
    __shared__ float sW[64 * 68];
    __shared__ float sx[1024];

    const int l = blockIdx.x, n = blockIdx.y, t = threadIdx.x;
    const int h = t >> 4, e0 = (t & 15) * 4;
    const float QSC = 1.44269504088896341f / 32.0f;

    const float* Xs[3] = {Xv, Xk, Xq};
    const float* Ws[3] = {Wv, Wk, Wq};

    for (int p = 0; p < 3; ++p) {
        __syncthreads();
        for (int i = t; i < 4096; i += 256) { int e = i >> 6, d = i & 63; sW[d * 68 + e] = Ws[p][i]; }
        ((float4*)sx)[t] = ((const float4*)(Xs[p] + ((size_t)n * LSEQ + l) * EMBED))[t];
        __syncthreads();

        float a0 = 0.f, a1 = 0.f, a2 = 0.f, a3 = 0.f;
        const float* xh = sx + h * 64;
        #pragma unroll 16
        for (int d = 0; d < 64; ++d) {
            float xv = xh[d];
            float4 w = *(const float4*)(sW + d * 68 + e0);
            a0 += xv * w.x; a1 += xv * w.y; a2 += xv * w.z; a3 += xv * w.w;
        }
        if (p == 0) {
            size_t base = (((size_t)n * HEADS + h) * HD + e0) * LSEQ + l;
            Vt[base           ] = bf16r(a0);
            Vt[base +     LSEQ] = bf16r(a1);
            Vt[base + 2 * LSEQ] = bf16r(a2);
            Vt[base + 3 * LSEQ] = bf16r(a3);
        } else {
            if (p == 2) { a0 *= QSC; a1 *= QSC; a2 *= QSC; a3 *= QSC; }
            unsigned short* dst = (p == 1) ? Kp : Qp;
            ushort4 v; v.x = bf16r(a0); v.y = bf16r(a1); v.z = bf16r(a2); v.w = bf16r(a3);
            *(ushort4*)(dst + (((size_t)n * HEADS + h) * LSEQ + l) * HD + e0) = v;
        }
    }
}

// ---------------------------------------------------------------------------
// Kernel 2: MFMA flash attention, S^T orientation.
//   S^T = K Q^T via mfma(A=Kfrag, B=Qfrag): C col = query (l5), rows = keys;
//   each reg quad holds 4 CONSECUTIVE keys -> packed b64 P stores, truncation
//   packing via v_perm, per-lane scalar row-sum.
//   PV: O[q][d] via mfma(A=Pfrag from sP, B=V^T frag from sV); sP is a tiny
//   per-wave 32q x 32k chunk consumed per-tc (same-wave in-order DS).
//   K/V tile prefetched into registers -> global latency drains at the next
//   LDS write, not mid-compute.  LDS = 16+16+8 = 40KB.
// ---------------------------------------------------------------------------
__global__ __launch_bounds__(256, 3) void attn_kernel(
    const unsigned short* __restrict__ Qp, const unsigned short* __restrict__ Kp,
    const unsigned short* __restrict__ Vt,
    unsigned short* __restrict__ AOh, unsigned short* __restrict__ AOl)
{
    __shared__ uint4 sK[128 * 8];    // [key][8 granules of 8 dims], swizzled   16KB
    __shared__ uint4 sV[64 * 16];    // [d][16 granules of 8 keys], swizzled    16KB
    __shared__ uint4 sP4[4 * 128];   // per-wave 32q x 32k bf16, swizzled        8KB

    const int t = threadIdx.x;
    const int lane = t & 63, w = t >> 6;
    const int l5 = lane & 31, hi = lane >> 5;
    const int n = blockIdx.z, h = blockIdx.y;
    const int q0 = blockIdx.x * 128;
    const size_t hoff = ((size_t)n * HEADS + h) * (size_t)(LSEQ * HD);
    const unsigned short* Kh = Kp + hoff;
    const unsigned short* Vh = Vt + hoff;

    // Q B-fragments (query = q0 + w*32 + l5), resident all loop
    bf16x8 qf[4];
    {
        const uint4* qg = (const uint4*)(Qp + hoff + (size_t)(q0 + w * 32 + l5) * HD);
        #pragma unroll
        for (int kc = 0; kc < 4; ++kc) qf[kc] = as_bf16x8(qg[kc * 2 + hi]);
    }

    f32x16 Oa0, Oa1;
    #pragma unroll
    for (int i = 0; i < 16; ++i) { Oa0[i] = 0.f; Oa1[i] = 0.f; }
    float lsum = 0.f;

    uint2*       sPw = (uint2*)(sP4 + w * 128);        // 8B units
    const uint4* sPq = sP4 + w * 128;                  // 16B units
    const int    psw = (l5 >> 1) & 3;                  // sP granule swizzle

    // ---- register prefetch of K/V tile ----
    uint4 rK[4], rV[4];
    {
        const uint4* gK = (const uint4*)Kh;
        #pragma unroll
        for (int i = 0; i < 4; ++i) rK[i] = gK[t + 256 * i];
        #pragma unroll
        for (int i = 0; i < 4; ++i) {
            int u = t + 256 * i; int d = u >> 4, kg = u & 15;
            rV[i] = *(const uint4*)(Vh + (size_t)d * LSEQ + kg * 8);
        }
    }

    for (int kt = 0; kt < LSEQ; kt += 128) {
        // ---- commit prefetched tile to LDS (swizzled) ----
        #pragma unroll
        for (int i = 0; i < 4; ++i) {
            int u = t + 256 * i; int key = u >> 3, gd = u & 7;
            sK[key * 8 + (gd ^ (key & 7))] = rK[i];
        }
        #pragma unroll
        for (int i = 0; i < 4; ++i) {
            int u = t + 256 * i; int d = u >> 4, kg = u & 15;
            sV[d * 16 + (kg ^ (d & 7))] = rV[i];
        }
        __syncthreads();

        // ---- prefetch next tile (no wait until next commit) ----
        if (kt + 128 < LSEQ) {
            const uint4* gK = (const uint4*)(Kh + (size_t)(kt + 128) * HD);
            #pragma unroll
            for (int i = 0; i < 4; ++i) rK[i] = gK[t + 256 * i];
            #pragma unroll
            for (int i = 0; i < 4; ++i) {
                int u = t + 256 * i; int d = u >> 4, kg = u & 15;
                rV[i] = *(const uint4*)(Vh + (size_t)d * LSEQ + (kt + 128) + kg * 8);
            }
        }

        #pragma unroll
        for (int tc = 0; tc < 4; ++tc) {
            // ---- S^T(32 keys x 32 queries) = K Q^T : 4 MFMA ----
            f32x16 c;
            #pragma unroll
            for (int i = 0; i < 16; ++i) c[i] = 0.f;
            int key = tc * 32 + l5;
            #pragma unroll
            for (int kc = 0; kc < 4; ++kc) {
                bf16x8 kf = as_bf16x8(sK[key * 8 + ((kc * 2 + hi) ^ (l5 & 7))]);
                c = __builtin_amdgcn_mfma_f32_32x32x16_bf16(kf, qf[kc], c, 0, 0, 0);
            }

            // ---- p = exp2(S); truncate-pack to bf16; lsum from SAME truncated
            //      values (softmax ratio unbiased); 4 consecutive keys/quad ----
            #pragma unroll
            for (int g = 0; g < 4; ++g) {
                float p0 = exp2f(c[4 * g]);
                float p1 = exp2f(c[4 * g + 1]);
                float p2 = exp2f(c[4 * g + 2]);
                float p3 = exp2f(c[4 * g + 3]);
                uint2 pk;
                pk.x = __builtin_amdgcn_perm(__float_as_uint(p1), __float_as_uint(p0), 0x07060302u);
                pk.y = __builtin_amdgcn_perm(__float_as_uint(p3), __float_as_uint(p2), 0x07060302u);
                lsum += (__uint_as_float(__float_as_uint(p0) & 0xffff0000u)
                       + __uint_as_float(__float_as_uint(p1) & 0xffff0000u))
                      + (__uint_as_float(__float_as_uint(p2) & 0xffff0000u)
                       + __uint_as_float(__float_as_uint(p3) & 0xffff0000u));
                // row q=l5, keys 8g+4hi+(0..3): 8B half (g^swz)*2+hi
                sPw[l5 * 8 + ((g ^ psw) << 1) + hi] = pk;
            }

            // ---- O += P V : per window of 16 keys, 2 MFMA ----
            #pragma unroll
            for (int win = 0; win < 2; ++win) {
                bf16x8 pf = as_bf16x8(sPq[l5 * 4 + (((win << 1) + hi) ^ psw)]);
                int vg = tc * 4 + (win << 1) + hi;
                bf16x8 v0 = as_bf16x8(sV[ l5       * 16 + (vg ^ (l5 & 7))]);
                Oa0 = __builtin_amdgcn_mfma_f32_32x32x16_bf16(pf, v0, Oa0, 0, 0, 0);
                bf16x8 v1 = as_bf16x8(sV[(32 + l5) * 16 + (vg ^ (l5 & 7))]);
                Oa1 = __builtin_amdgcn_mfma_f32_32x32x16_bf16(pf, v1, Oa1, 0, 0, 0);
            }
        }
        __syncthreads();
    }

    // ---- denominators: lane holds partial for query l5; combine hi halves ----
    lsum += __shfl_xor(lsum, 32);
    float inv = 1.0f / lsum;
    float* sLf = (float*)sK;                 // reuse K LDS (per-wave region)
    if (hi == 0) sLf[w * 32 + l5] = inv;     // both hi halves have same value

    // ---- scale + split-bf16 store: lane holds O[q_r][d=l5 / 32+l5] ----
    unsigned short* hB = AOh + hoff;
    unsigned short* lB = AOl + hoff;
    #pragma unroll
    for (int r = 0; r < 16; ++r) {
        int qr = (r & 3) + 8 * (r >> 2) + 4 * hi;
        float invq = sLf[w * 32 + qr];       // same addr all lanes: broadcast
        size_t row = (size_t)(q0 + w * 32 + qr) * HD;
        float o0 = Oa0[r] * invq;
        float o1 = Oa1[r] * invq;
        unsigned short h0 = bf16r(o0), h1 = bf16r(o1);
        hB[row +      l5] = h0;
        hB[row + 32 + l5] = h1;
        lB[row +      l5] = bf16r(o0 - bfh2f(h0));
        lB[row + 32 + l5] = bf16r(o1 - bfh2f(h1));
    }
}

// ---------------------------------------------------------------------------
// Kernel 2.5: split Wo into bf16 hi/lo (unchanged).
// ---------------------------------------------------------------------------
__global__ __launch_bounds__(256) void wsplit_kernel(
    const float* __restrict__ Wo,
    unsigned short* __restrict__ Woh, unsigned short* __restrict__ Wol)
{
    int i = blockIdx.x * 256 + threadIdx.x;
    float4 v = ((const float4*)Wo)[i];
    ushort4 h, l;
    h.x = bf16r(v.x); l.x = bf16r(v.x - bfh2f(h.x));
    h.y = bf16r(v.y); l.y = bf16r(v.y - bfh2f(h.y));
    h.z = bf16r(v.z); l.z = bf16r(v.z - bfh2f(h.z));
    h.w = bf16r(v.w); l.w = bf16r(v.w - bfh2f(h.w));
    ((ushort4*)Woh)[i] = h;
    ((ushort4*)Wol)[i] = l;
}

// ---------------------------------------------------------------------------
// Kernel 3: output projection, split-bf16 MFMA GEMM (unchanged from R3).
// ---------------------------------------------------------------------------
__global__ __launch_bounds__(256, 2) void outproj_kernel(
    const unsigned short* __restrict__ AOh, const unsigned short* __restrict__ AOl,
    const unsigned short* __restrict__ Woh, const unsigned short* __restrict__ Wol,
    const float* __restrict__ bo, float* __restrict__ out)
{
    __shared__ uint4 sAh[1024];
    __shared__ uint4 sAl[1024];
    __shared__ uint4 sBh[1024];
    __shared__ uint4 sBl[1024];

    const int t = threadIdx.x;
    const int lane = t & 63, w = t >> 6;
    const int l5 = lane & 31, hi = lane >> 5;
    const int m0 = blockIdx.x * 128;
    const int e0 = blockIdx.y * 128;
    const int n  = m0 >> 11, l0 = m0 & 2047;
    const int mr = (w & 1) * 64, nc = (w >> 1) * 64;

    f32x16 acc[2][2];
    #pragma unroll
    for (int a = 0; a < 2; ++a)
        #pragma unroll
        for (int b = 0; b < 2; ++b)
            #pragma unroll
            for (int i = 0; i < 16; ++i) acc[a][b][i] = 0.f;

    for (int hh = 0; hh < 16; ++hh) {
        const unsigned short* Ah = AOh + ((((size_t)n * HEADS + hh) * LSEQ) + l0) * HD;
        const unsigned short* Al = AOl + ((((size_t)n * HEADS + hh) * LSEQ) + l0) * HD;
        #pragma unroll
        for (int i = 0; i < 4; ++i) {
            int g = t + i * 256;
            gload_lds16(Ah + g * 8, sAh + g);
            gload_lds16(Al + g * 8, sAl + g);
            int e = g >> 3, gf = g & 7;
            size_t boff = (size_t)(e0 + e) * EMBED + hh * 64 + gf * 8;
            gload_lds16(Woh + boff, sBh + g);
            gload_lds16(Wol + boff, sBl + g);
        }
        __syncthreads();

        #pragma unroll
        for (int s = 0; s < 4; ++s) {
            int gcol = s * 2 + hi;
            bf16x8 ah0 = as_bf16x8(sAh[(mr +      l5) * 8 + gcol]);
            bf16x8 ah1 = as_bf16x8(sAh[(mr + 32 + l5) * 8 + gcol]);
            bf16x8 al0 = as_bf16x8(sAl[(mr +      l5) * 8 + gcol]);
            bf16x8 al1 = as_bf16x8(sAl[(mr + 32 + l5) * 8 + gcol]);
            bf16x8 bh0 = as_bf16x8(sBh[(nc +      l5) * 8 + gcol]);
            bf16x8 bh1 = as_bf16x8(sBh[(nc + 32 + l5) * 8 + gcol]);
            bf16x8 bl0 = as_bf16x8(sBl[(nc +      l5) * 8 + gcol]);
            bf16x8 bl1 = as_bf16x8(sBl[(nc + 32 + l5) * 8 + gcol]);

            acc[0][0] = __builtin_amdgcn_mfma_f32_32x32x16_bf16(ah0, bh0, acc[0][0], 0, 0, 0);
            acc[0][1] = __builtin_amdgcn_mfma_f32_32x32x16_bf16(ah0, bh1, acc[0][1], 0, 0, 0);
            acc[1][0] = __builtin_amdgcn_mfma_f32_32x32x16_bf16(ah1, bh0, acc[1][0], 0, 0, 0);
            acc[1][1] = __builtin_amdgcn_mfma_f32_32x32x16_bf16(ah1, bh1, acc[1][1], 0, 0, 0);

            acc[0][0] = __builtin_amdgcn_mfma_f32_32x32x16_bf16(ah0, bl0, acc[0][0], 0, 0, 0);
            acc[0][1] = __builtin_amdgcn_mfma_f32_32x32x16_bf16(ah0, bl1, acc[0][1], 0, 0, 0);
            acc[1][0] = __builtin_amdgcn_mfma_f32_32x32x16_bf16(ah1, bl0, acc[1][0], 0, 0, 0);
            acc[1][1] = __builtin_amdgcn_mfma_f32_32x32x16_bf16(ah1, bl1, acc[1][1], 0, 0, 0);

            acc[0][0] = __builtin_amdgcn_mfma_f32_32x32x16_bf16(al0, bh0, acc[0][0], 0, 0, 0);
            acc[0][1] = __builtin_amdgcn_mfma_f32_32x32x16_bf16(al0, bh1, acc[0][1], 0, 0, 0);
            acc[1][0] = __builtin_amdgcn_mfma_f32_32x32x16_bf16(al1, bh0, acc[1][0], 0, 0, 0);
            acc[1][1] = __builtin_amdgcn_mfma_f32_32x32x16_bf16(al1, bh1, acc[1][1], 0, 0, 0);
        }
        __syncthreads();
    }

    float b0 = bo[e0 + nc + l5];
    float b1 = bo[e0 + nc + 32 + l5];
    #pragma unroll
    for (int ti = 0; ti < 2; ++ti) {
        #pragma unroll
        for (int r = 0; r < 16; ++r) {
            int row = m0 + mr + ti * 32 + (r & 3) + 8 * (r >> 2) + 4 * hi;
            float* o = out + (size_t)row * EMBED + e0 + nc;
            o[l5]      = acc[ti][0][r] + b0;
            o[32 + l5] = acc[ti][1][r] + b1;
        }
    }
}

// ---------------------------------------------------------------------------
extern "C" void kernel_launch(void* const* d_in, const int* in_sizes, int n_in,
                              void* d_out, int out_size, void* d_ws, size_t ws_size,
                              hipStream_t stream)
{
    const float* values  = (const float*)d_in[0];
    const float* keys    = (const float*)d_in[1];
    const float* queries = (const float*)d_in[2];
    const float* Wv      = (const float*)d_in[3];
    const float* Wk      = (const float*)d_in[4];
    const float* Wq      = (const float*)d_in[5];
    const float* Wo      = (const float*)d_in[6];
    const float* bo      = (const float*)d_in[7];
    float* out = (float*)d_out;

    const size_t bufElems = (size_t)NB * HEADS * LSEQ * HD;   // 8,388,608
    unsigned short* Qp  = (unsigned short*)d_ws;
    unsigned short* Kp  = Qp  + bufElems;
    unsigned short* Vt  = Kp  + bufElems;
    unsigned short* AOh = Vt  + bufElems;
    unsigned short* AOl = AOh + bufElems;
    unsigned short* Woh = AOl + bufElems;
    unsigned short* Wol = Woh + (size_t)EMBED * EMBED;

    wsplit_kernel<<<dim3(1024), 256, 0, stream>>>(Wo, Woh, Wol);
    proj_kernel<<<dim3(LSEQ, NB), 256, 0, stream>>>(values, keys, queries, Wv, Wk, Wq, Vt, Kp, Qp);
    attn_kernel<<<dim3(LSEQ / 128, HEADS, NB), 256, 0, stream>>>(Qp, Kp, Vt, AOh, AOl);
    outproj_kernel<<<dim3(NB * LSEQ / 128, EMBED / 128), 256, 0, stream>>>(AOh, AOl, Woh, Wol, bo, out);
}

// Round 5
// 460.337 us; speedup vs baseline: 1.1690x; 1.1690x over previous
//
#include <hip/hip_runtime.h>
#include <math.h>

#define EMBED 1024
#define HEADS 16
#define HD    64
#define NB    4
#define LSEQ  2048

typedef __attribute__((ext_vector_type(8))) short bf16x8;
typedef __attribute__((ext_vector_type(16))) float f32x16;

typedef __attribute__((address_space(1))) void as1_void;
typedef __attribute__((address_space(3))) void as3_void;

__device__ __forceinline__ void gload_lds16(const void* g, void* l) {
    __builtin_amdgcn_global_load_lds((const as1_void*)g, (as3_void*)l, 16, 0, 0);
}

__device__ inline bf16x8 as_bf16x8(uint4 u) {
    union { uint4 u; bf16x8 b; } c; c.u = u; return c.b;
}
// round-to-nearest-even fp32 -> bf16 (raw ushort); finite inputs only
__device__ inline unsigned short bf16r(float x) {
    unsigned u = __float_as_uint(x);
    u += 0x7fffu + ((u >> 16) & 1u);
    return (unsigned short)(u >> 16);
}
__device__ inline float bfh2f(unsigned short h) {
    return __uint_as_float(((unsigned)h) << 16);
}

// ---------------------------------------------------------------------------
// Kernel 1: per-head QKV projections -> bf16 (unchanged).
// ---------------------------------------------------------------------------
__global__ __launch_bounds__(256) void proj_kernel(
    const float* __restrict__ Xv, const float* __restrict__ Xk, const float* __restrict__ Xq,
    const float* __restrict__ Wv, const float* __restrict__ Wk, const float* __restrict__ Wq,
    unsigned short* __restrict__ Vt, unsigned short* __restrict__ Kp, unsigned short* __restrict__ Qp)
{
    __shared__ float sW[64 * 68];
    __shared__ float sx[1024];

    const int l = blockIdx.x, n = blockIdx.y, t = threadIdx.x;
    const int h = t >> 4, e0 = (t & 15) * 4;
    const float QSC = 1.44269504088896341f / 32.0f;

    const float* Xs[3] = {Xv, Xk, Xq};
    const float* Ws[3] = {Wv, Wk, Wq};

    for (int p = 0; p < 3; ++p) {
        __syncthreads();
        for (int i = t; i < 4096; i += 256) { int e = i >> 6, d = i & 63; sW[d * 68 + e] = Ws[p][i]; }
        ((float4*)sx)[t] = ((const float4*)(Xs[p] + ((size_t)n * LSEQ + l) * EMBED))[t];
        __syncthreads();

        float a0 = 0.f, a1 = 0.f, a2 = 0.f, a3 = 0.f;
        const float* xh = sx + h * 64;
        #pragma unroll 16
        for (int d = 0; d < 64; ++d) {
            float xv = xh[d];
            float4 w = *(const float4*)(sW + d * 68 + e0);
            a0 += xv * w.x; a1 += xv * w.y; a2 += xv * w.z; a3 += xv * w.w;
        }
        if (p == 0) {
            size_t base = (((size_t)n * HEADS + h) * HD + e0) * LSEQ + l;
            Vt[base           ] = bf16r(a0);
            Vt[base +     LSEQ] = bf16r(a1);
            Vt[base + 2 * LSEQ] = bf16r(a2);
            Vt[base + 3 * LSEQ] = bf16r(a3);
        } else {
            if (p == 2) { a0 *= QSC; a1 *= QSC; a2 *= QSC; a3 *= QSC; }
            unsigned short* dst = (p == 1) ? Kp : Qp;
            ushort4 v; v.x = bf16r(a0); v.y = bf16r(a1); v.z = bf16r(a2); v.w = bf16r(a3);
            *(ushort4*)(dst + (((size_t)n * HEADS + h) * LSEQ + l) * HD + e0) = v;
        }
    }
}

// ---------------------------------------------------------------------------
// Kernel 2: MFMA flash attention, S^T orientation (R4 structure, NO register
// prefetch — that spilled under the 3-waves/EU budget and cost 500MB of
// scratch HBM traffic).  Direct global->LDS staging as in R3.
// LDS = 16+16+8 = 40KB -> 3 blocks/CU at <=170 regs.
// ---------------------------------------------------------------------------
__global__ __launch_bounds__(256, 3) void attn_kernel(
    const unsigned short* __restrict__ Qp, const unsigned short* __restrict__ Kp,
    const unsigned short* __restrict__ Vt,
    unsigned short* __restrict__ AOh, unsigned short* __restrict__ AOl)
{
    __shared__ uint4 sK[128 * 8];    // [key][8 granules of 8 dims], swizzled   16KB
    __shared__ uint4 sV[64 * 16];    // [d][16 granules of 8 keys], swizzled    16KB
    __shared__ uint4 sP4[4 * 128];   // per-wave 32q x 32k bf16, swizzled        8KB

    const int t = threadIdx.x;
    const int lane = t & 63, w = t >> 6;
    const int l5 = lane & 31, hi = lane >> 5;
    const int n = blockIdx.z, h = blockIdx.y;
    const int q0 = blockIdx.x * 128;
    const size_t hoff = ((size_t)n * HEADS + h) * (size_t)(LSEQ * HD);
    const unsigned short* Kh = Kp + hoff;
    const unsigned short* Vh = Vt + hoff;

    // Q B-fragments (query = q0 + w*32 + l5), resident all loop
    bf16x8 qf[4];
    {
        const uint4* qg = (const uint4*)(Qp + hoff + (size_t)(q0 + w * 32 + l5) * HD);
        #pragma unroll
        for (int kc = 0; kc < 4; ++kc) qf[kc] = as_bf16x8(qg[kc * 2 + hi]);
    }

    f32x16 Oa0, Oa1;
    #pragma unroll
    for (int i = 0; i < 16; ++i) { Oa0[i] = 0.f; Oa1[i] = 0.f; }
    float lsum = 0.f;

    uint2*       sPw = (uint2*)(sP4 + w * 128);        // 8B units
    const uint4* sPq = sP4 + w * 128;                  // 16B units
    const int    psw = (l5 >> 1) & 3;                  // sP granule swizzle

    for (int kt = 0; kt < LSEQ; kt += 128) {
        // ---- stage K/V tile, swizzled (load sits directly before store;
        //      TLP at 12 waves/CU hides the global latency) ----
        const uint4* gK = (const uint4*)(Kh + (size_t)kt * HD);
        #pragma unroll
        for (int i = 0; i < 4; ++i) {
            int u = t + 256 * i; int key = u >> 3, gd = u & 7;
            sK[key * 8 + (gd ^ (key & 7))] = gK[u];
        }
        #pragma unroll
        for (int i = 0; i < 4; ++i) {
            int u = t + 256 * i; int d = u >> 4, kg = u & 15;
            sV[d * 16 + (kg ^ (d & 7))] = *(const uint4*)(Vh + (size_t)d * LSEQ + kt + kg * 8);
        }
        __syncthreads();

        #pragma unroll
        for (int tc = 0; tc < 4; ++tc) {
            // ---- S^T(32 keys x 32 queries) = K Q^T : 4 MFMA ----
            f32x16 c;
            #pragma unroll
            for (int i = 0; i < 16; ++i) c[i] = 0.f;
            int key = tc * 32 + l5;
            #pragma unroll
            for (int kc = 0; kc < 4; ++kc) {
                bf16x8 kf = as_bf16x8(sK[key * 8 + ((kc * 2 + hi) ^ (l5 & 7))]);
                c = __builtin_amdgcn_mfma_f32_32x32x16_bf16(kf, qf[kc], c, 0, 0, 0);
            }

            // ---- p = exp2(S); truncate-pack to bf16; lsum from SAME truncated
            //      values (softmax ratio unbiased); 4 consecutive keys/quad ----
            #pragma unroll
            for (int g = 0; g < 4; ++g) {
                float p0 = exp2f(c[4 * g]);
                float p1 = exp2f(c[4 * g + 1]);
                float p2 = exp2f(c[4 * g + 2]);
                float p3 = exp2f(c[4 * g + 3]);
                uint2 pk;
                pk.x = __builtin_amdgcn_perm(__float_as_uint(p1), __float_as_uint(p0), 0x07060302u);
                pk.y = __builtin_amdgcn_perm(__float_as_uint(p3), __float_as_uint(p2), 0x07060302u);
                lsum += (__uint_as_float(__float_as_uint(p0) & 0xffff0000u)
                       + __uint_as_float(__float_as_uint(p1) & 0xffff0000u))
                      + (__uint_as_float(__float_as_uint(p2) & 0xffff0000u)
                       + __uint_as_float(__float_as_uint(p3) & 0xffff0000u));
                sPw[l5 * 8 + ((g ^ psw) << 1) + hi] = pk;
            }

            // ---- O += P V : per window of 16 keys, 2 MFMA ----
            #pragma unroll
            for (int win = 0; win < 2; ++win) {
                bf16x8 pf = as_bf16x8(sPq[l5 * 4 + (((win << 1) + hi) ^ psw)]);
                int vg = tc * 4 + (win << 1) + hi;
                bf16x8 v0 = as_bf16x8(sV[ l5       * 16 + (vg ^ (l5 & 7))]);
                Oa0 = __builtin_amdgcn_mfma_f32_32x32x16_bf16(pf, v0, Oa0, 0, 0, 0);
                bf16x8 v1 = as_bf16x8(sV[(32 + l5) * 16 + (vg ^ (l5 & 7))]);
                Oa1 = __builtin_amdgcn_mfma_f32_32x32x16_bf16(pf, v1, Oa1, 0, 0, 0);
            }
        }
        __syncthreads();
    }

    // ---- denominators: lane holds partial for query l5; combine hi halves ----
    lsum += __shfl_xor(lsum, 32);
    float inv = 1.0f / lsum;
    float* sLf = (float*)sK;                 // reuse K LDS (per-wave region)
    if (hi == 0) sLf[w * 32 + l5] = inv;

    // ---- scale + split-bf16 store: lane holds O[q_r][d=l5 / 32+l5] ----
    unsigned short* hB = AOh + hoff;
    unsigned short* lB = AOl + hoff;
    #pragma unroll
    for (int r = 0; r < 16; ++r) {
        int qr = (r & 3) + 8 * (r >> 2) + 4 * hi;
        float invq = sLf[w * 32 + qr];
        size_t row = (size_t)(q0 + w * 32 + qr) * HD;
        float o0 = Oa0[r] * invq;
        float o1 = Oa1[r] * invq;
        unsigned short h0 = bf16r(o0), h1 = bf16r(o1);
        hB[row +      l5] = h0;
        hB[row + 32 + l5] = h1;
        lB[row +      l5] = bf16r(o0 - bfh2f(h0));
        lB[row + 32 + l5] = bf16r(o1 - bfh2f(h1));
    }
}

// ---------------------------------------------------------------------------
// Kernel 2.5: split Wo into bf16 hi/lo (unchanged).
// ---------------------------------------------------------------------------
__global__ __launch_bounds__(256) void wsplit_kernel(
    const float* __restrict__ Wo,
    unsigned short* __restrict__ Woh, unsigned short* __restrict__ Wol)
{
    int i = blockIdx.x * 256 + threadIdx.x;
    float4 v = ((const float4*)Wo)[i];
    ushort4 h, l;
    h.x = bf16r(v.x); l.x = bf16r(v.x - bfh2f(h.x));
    h.y = bf16r(v.y); l.y = bf16r(v.y - bfh2f(h.y));
    h.z = bf16r(v.z); l.z = bf16r(v.z - bfh2f(h.z));
    h.w = bf16r(v.w); l.w = bf16r(v.w - bfh2f(h.w));
    ((ushort4*)Woh)[i] = h;
    ((ushort4*)Wol)[i] = l;
}

// ---------------------------------------------------------------------------
// Kernel 3: output projection, split-bf16 MFMA GEMM (unchanged).
// ---------------------------------------------------------------------------
__global__ __launch_bounds__(256, 2) void outproj_kernel(
    const unsigned short* __restrict__ AOh, const unsigned short* __restrict__ AOl,
    const unsigned short* __restrict__ Woh, const unsigned short* __restrict__ Wol,
    const float* __restrict__ bo, float* __restrict__ out)
{
    __shared__ uint4 sAh[1024];
    __shared__ uint4 sAl[1024];
    __shared__ uint4 sBh[1024];
    __shared__ uint4 sBl[1024];

    const int t = threadIdx.x;
    const int lane = t & 63, w = t >> 6;
    const int l5 = lane & 31, hi = lane >> 5;
    const int m0 = blockIdx.x * 128;
    const int e0 = blockIdx.y * 128;
    const int n  = m0 >> 11, l0 = m0 & 2047;
    const int mr = (w & 1) * 64, nc = (w >> 1) * 64;

    f32x16 acc[2][2];
    #pragma unroll
    for (int a = 0; a < 2; ++a)
        #pragma unroll
        for (int b = 0; b < 2; ++b)
            #pragma unroll
            for (int i = 0; i < 16; ++i) acc[a][b][i] = 0.f;

    for (int hh = 0; hh < 16; ++hh) {
        const unsigned short* Ah = AOh + ((((size_t)n * HEADS + hh) * LSEQ) + l0) * HD;
        const unsigned short* Al = AOl + ((((size_t)n * HEADS + hh) * LSEQ) + l0) * HD;
        #pragma unroll
        for (int i = 0; i < 4; ++i) {
            int g = t + i * 256;
            gload_lds16(Ah + g * 8, sAh + g);
            gload_lds16(Al + g * 8, sAl + g);
            int e = g >> 3, gf = g & 7;
            size_t boff = (size_t)(e0 + e) * EMBED + hh * 64 + gf * 8;
            gload_lds16(Woh + boff, sBh + g);
            gload_lds16(Wol + boff, sBl + g);
        }
        __syncthreads();

        #pragma unroll
        for (int s = 0; s < 4; ++s) {
            int gcol = s * 2 + hi;
            bf16x8 ah0 = as_bf16x8(sAh[(mr +      l5) * 8 + gcol]);
            bf16x8 ah1 = as_bf16x8(sAh[(mr + 32 + l5) * 8 + gcol]);
            bf16x8 al0 = as_bf16x8(sAl[(mr +      l5) * 8 + gcol]);
            bf16x8 al1 = as_bf16x8(sAl[(mr + 32 + l5) * 8 + gcol]);
            bf16x8 bh0 = as_bf16x8(sBh[(nc +      l5) * 8 + gcol]);
            bf16x8 bh1 = as_bf16x8(sBh[(nc + 32 + l5) * 8 + gcol]);
            bf16x8 bl0 = as_bf16x8(sBl[(nc +      l5) * 8 + gcol]);
            bf16x8 bl1 = as_bf16x8(sBl[(nc + 32 + l5) * 8 + gcol]);

            acc[0][0] = __builtin_amdgcn_mfma_f32_32x32x16_bf16(ah0, bh0, acc[0][0], 0, 0, 0);
            acc[0][1] = __builtin_amdgcn_mfma_f32_32x32x16_bf16(ah0, bh1, acc[0][1], 0, 0, 0);
            acc[1][0] = __builtin_amdgcn_mfma_f32_32x32x16_bf16(ah1, bh0, acc[1][0], 0, 0, 0);
            acc[1][1] = __builtin_amdgcn_mfma_f32_32x32x16_bf16(ah1, bh1, acc[1][1], 0, 0, 0);

            acc[0][0] = __builtin_amdgcn_mfma_f32_32x32x16_bf16(ah0, bl0, acc[0][0], 0, 0, 0);
            acc[0][1] = __builtin_amdgcn_mfma_f32_32x32x16_bf16(ah0, bl1, acc[0][1], 0, 0, 0);
            acc[1][0] = __builtin_amdgcn_mfma_f32_32x32x16_bf16(ah1, bl0, acc[1][0], 0, 0, 0);
            acc[1][1] = __builtin_amdgcn_mfma_f32_32x32x16_bf16(ah1, bl1, acc[1][1], 0, 0, 0);

            acc[0][0] = __builtin_amdgcn_mfma_f32_32x32x16_bf16(al0, bh0, acc[0][0], 0, 0, 0);
            acc[0][1] = __builtin_amdgcn_mfma_f32_32x32x16_bf16(al0, bh1, acc[0][1], 0, 0, 0);
            acc[1][0] = __builtin_amdgcn_mfma_f32_32x32x16_bf16(al1, bh0, acc[1][0], 0, 0, 0);
            acc[1][1] = __builtin_amdgcn_mfma_f32_32x32x16_bf16(al1, bh1, acc[1][1], 0, 0, 0);
        }
        __syncthreads();
    }

    float b0 = bo[e0 + nc + l5];
    float b1 = bo[e0 + nc + 32 + l5];
    #pragma unroll
    for (int ti = 0; ti < 2; ++ti) {
        #pragma unroll
        for (int r = 0; r < 16; ++r) {
            int row = m0 + mr + ti * 32 + (r & 3) + 8 * (r >> 2) + 4 * hi;
            float* o = out + (size_t)row * EMBED + e0 + nc;
            o[l5]      = acc[ti][0][r] + b0;
            o[32 + l5] = acc[ti][1][r] + b1;
        }
    }
}

// ---------------------------------------------------------------------------
extern "C" void kernel_launch(void* const* d_in, const int* in_sizes, int n_in,
                              void* d_out, int out_size, void* d_ws, size_t ws_size,
                              hipStream_t stream)
{
    const float* values  = (const float*)d_in[0];
    const float* keys    = (const float*)d_in[1];
    const float* queries = (const float*)d_in[2];
    const float* Wv      = (const float*)d_in[3];
    const float* Wk      = (const float*)d_in[4];
    const float* Wq      = (const float*)d_in[5];
    const float* Wo      = (const float*)d_in[6];
    const float* bo      = (const float*)d_in[7];
    float* out = (float*)d_out;

    const size_t bufElems = (size_t)NB * HEADS * LSEQ * HD;   // 8,388,608
    unsigned short* Qp  = (unsigned short*)d_ws;
    unsigned short* Kp  = Qp  + bufElems;
    unsigned short* Vt  = Kp  + bufElems;
    unsigned short* AOh = Vt  + bufElems;
    unsigned short* AOl = AOh + bufElems;
    unsigned short* Woh = AOl + bufElems;
    unsigned short* Wol = Woh + (size_t)EMBED * EMBED;

    wsplit_kernel<<<dim3(1024), 256, 0, stream>>>(Wo, Woh, Wol);
    proj_kernel<<<dim3(LSEQ, NB), 256, 0, stream>>>(values, keys, queries, Wv, Wk, Wq, Vt, Kp, Qp);
    attn_kernel<<<dim3(LSEQ / 128, HEADS, NB), 256, 0, stream>>>(Qp, Kp, Vt, AOh, AOl);
    outproj_kernel<<<dim3(NB * LSEQ / 128, EMBED / 128), 256, 0, stream>>>(AOh, AOl, Woh, Wol, bo, out);
}

// Round 6
// 379.472 us; speedup vs baseline: 1.4181x; 1.2131x over previous
//
#include <hip/hip_runtime.h>
#include <math.h>

#define EMBED 1024
#define HEADS 16
#define HD    64
#define NB    4
#define LSEQ  2048

typedef __attribute__((ext_vector_type(8))) short bf16x8;
typedef __attribute__((ext_vector_type(16))) float f32x16;

typedef __attribute__((address_space(1))) void as1_void;
typedef __attribute__((address_space(3))) void as3_void;

__device__ __forceinline__ void gload_lds16(const void* g, void* l) {
    __builtin_amdgcn_global_load_lds((const as1_void*)g, (as3_void*)l, 16, 0, 0);
}

__device__ inline bf16x8 as_bf16x8(uint4 u) {
    union { uint4 u; bf16x8 b; } c; c.u = u; return c.b;
}
// round-to-nearest-even fp32 -> bf16 (raw ushort); finite inputs only
__device__ inline unsigned short bf16r(float x) {
    unsigned u = __float_as_uint(x);
    u += 0x7fffu + ((u >> 16) & 1u);
    return (unsigned short)(u >> 16);
}
__device__ inline float bfh2f(unsigned short h) {
    return __uint_as_float(((unsigned)h) << 16);
}
// split two floats into packed hi/lo bf16 words
__device__ inline void split2(float x, float y, unsigned& hw, unsigned& lw) {
    unsigned short hx = bf16r(x), hy = bf16r(y);
    unsigned short lx = bf16r(x - bfh2f(hx)), ly = bf16r(y - bfh2f(hy));
    hw = (unsigned)hx | ((unsigned)hy << 16);
    lw = (unsigned)lx | ((unsigned)ly << 16);
}

// ---------------------------------------------------------------------------
// Kernel 1: QKV projections as split-bf16 MFMA GEMM.
// Block = 128 tokens x 1 head; 3 phases (V,K,Q) reuse LDS.
// X tile 128x64 fp32 -> split hi/lo bf16 in LDS (XOR-swizzled granules);
// W 64x64 fp32 -> split hi/lo in LDS.  C = Xh*Wh + Xh*Wl + Xl*Wh (fp32-level
// accuracy, same numerics as the old VALU version).
// V phase swaps MFMA operands to emit V^T directly (lane = token column ->
// coalesced Vt stores; fixes the 110MB write amplification seen in R5).
// LDS = 16+16+8+8 = 48KB -> 3 blocks/CU.
// ---------------------------------------------------------------------------
__global__ __launch_bounds__(256, 3) void proj_kernel(
    const float* __restrict__ Xv, const float* __restrict__ Xk, const float* __restrict__ Xq,
    const float* __restrict__ Wv, const float* __restrict__ Wk, const float* __restrict__ Wq,
    unsigned short* __restrict__ Vt, unsigned short* __restrict__ Kp, unsigned short* __restrict__ Qp)
{
    __shared__ uint4 sXh[128 * 8];   // [token][granule of 8 dims]  16KB
    __shared__ uint4 sXl[128 * 8];   // 16KB
    __shared__ uint4 sWh[64 * 8];    // [e][granule of 8 dims]       8KB
    __shared__ uint4 sWl[64 * 8];    //                              8KB

    const int t = threadIdx.x;
    const int lane = t & 63, w = t >> 6;
    const int l5 = lane & 31, hi = lane >> 5;
    const int h  = blockIdx.y;
    const int n  = blockIdx.x >> 4;
    const int l0 = (blockIdx.x & 15) * 128;

    const float QSC = 1.44269504088896341f / 32.0f;
    const float* Xs[3] = {Xv, Xk, Xq};
    const float* Ws[3] = {Wv, Wk, Wq};

    const int sr = t >> 1;          // staging row 0..127
    const int sh = t & 1;           // which half (32 dims) of the row

    for (int p = 0; p < 3; ++p) {
        __syncthreads();
        // ---- stage X tile: 128 rows x 64 dims fp32 -> hi/lo bf16, swizzled ----
        {
            const float* xb = Xs[p] + ((size_t)(n * LSEQ + l0 + sr)) * EMBED + h * HD + sh * 32;
            unsigned short* dh = (unsigned short*)sXh;
            unsigned short* dl = (unsigned short*)sXl;
            #pragma unroll
            for (int i = 0; i < 8; ++i) {
                float4 v = *(const float4*)(xb + i * 4);
                int j  = sh * 8 + i;              // float4 index within row
                int gg = j >> 1, s8 = (j & 1) * 4;
                int idx = sr * 64 + ((gg ^ (sr & 7)) * 8) + s8;
                uint2 hv, lv;
                split2(v.x, v.y, hv.x, lv.x);
                split2(v.z, v.w, hv.y, lv.y);
                *(uint2*)(dh + idx) = hv;
                *(uint2*)(dl + idx) = lv;
            }
        }
        // ---- stage W: 64x64 fp32 -> hi/lo bf16, swizzled ----
        #pragma unroll
        for (int i = 0; i < 2; ++i) {
            int u = t + 256 * i;                  // granule 0..511
            int e = u >> 3, g = u & 7;
            const float* wb = Ws[p] + u * 8;
            float4 v0 = *(const float4*)(wb);
            float4 v1 = *(const float4*)(wb + 4);
            uint4 hq, lq;
            split2(v0.x, v0.y, hq.x, lq.x);
            split2(v0.z, v0.w, hq.y, lq.y);
            split2(v1.x, v1.y, hq.z, lq.z);
            split2(v1.z, v1.w, hq.w, lq.w);
            int idx = e * 8 + (g ^ (e & 7));
            sWh[idx] = hq;
            sWl[idx] = lq;
        }
        __syncthreads();

        // ---- MFMA: per wave, 32-token tile x (two 32-wide e-tiles) ----
        f32x16 acc0, acc1;
        #pragma unroll
        for (int i = 0; i < 16; ++i) { acc0[i] = 0.f; acc1[i] = 0.f; }

        const int xrow = w * 32 + l5;
        const int w0r = l5, w1r = 32 + l5;
        #pragma unroll
        for (int kc = 0; kc < 4; ++kc) {
            int gsel = kc * 2 + hi;
            bf16x8 xh = as_bf16x8(sXh[xrow * 8 + (gsel ^ (xrow & 7))]);
            bf16x8 xl = as_bf16x8(sXl[xrow * 8 + (gsel ^ (xrow & 7))]);
            bf16x8 wh0 = as_bf16x8(sWh[w0r * 8 + (gsel ^ (w0r & 7))]);
            bf16x8 wl0 = as_bf16x8(sWl[w0r * 8 + (gsel ^ (w0r & 7))]);
            bf16x8 wh1 = as_bf16x8(sWh[w1r * 8 + (gsel ^ (w1r & 7))]);
            bf16x8 wl1 = as_bf16x8(sWl[w1r * 8 + (gsel ^ (w1r & 7))]);
            if (p == 0) {
                // V^T = W X^T : A=W-frag (rows e), B=X-frag (cols token)
                acc0 = __builtin_amdgcn_mfma_f32_32x32x16_bf16(wh0, xh, acc0, 0, 0, 0);
                acc0 = __builtin_amdgcn_mfma_f32_32x32x16_bf16(wh0, xl, acc0, 0, 0, 0);
                acc0 = __builtin_amdgcn_mfma_f32_32x32x16_bf16(wl0, xh, acc0, 0, 0, 0);
                acc1 = __builtin_amdgcn_mfma_f32_32x32x16_bf16(wh1, xh, acc1, 0, 0, 0);
                acc1 = __builtin_amdgcn_mfma_f32_32x32x16_bf16(wh1, xl, acc1, 0, 0, 0);
                acc1 = __builtin_amdgcn_mfma_f32_32x32x16_bf16(wl1, xh, acc1, 0, 0, 0);
            } else {
                // C = X W^T : A=X-frag (rows token), B=W-frag (cols e)
                acc0 = __builtin_amdgcn_mfma_f32_32x32x16_bf16(xh, wh0, acc0, 0, 0, 0);
                acc0 = __builtin_amdgcn_mfma_f32_32x32x16_bf16(xh, wl0, acc0, 0, 0, 0);
                acc0 = __builtin_amdgcn_mfma_f32_32x32x16_bf16(xl, wh0, acc0, 0, 0, 0);
                acc1 = __builtin_amdgcn_mfma_f32_32x32x16_bf16(xh, wh1, acc1, 0, 0, 0);
                acc1 = __builtin_amdgcn_mfma_f32_32x32x16_bf16(xh, wl1, acc1, 0, 0, 0);
                acc1 = __builtin_amdgcn_mfma_f32_32x32x16_bf16(xl, wh1, acc1, 0, 0, 0);
            }
        }

        // ---- epilogue ----
        if (p == 0) {
            // C rows = e, cols = token (V^T): coalesced Vt [N,H,D,L] stores
            unsigned short* vb = Vt + (((size_t)(n * HEADS + h)) * HD) * LSEQ + l0 + w * 32 + l5;
            #pragma unroll
            for (int r = 0; r < 16; ++r) {
                int er = (r & 3) + 8 * (r >> 2) + 4 * hi;
                vb[(size_t)er * LSEQ]        = bf16r(acc0[r]);
                vb[(size_t)(32 + er) * LSEQ] = bf16r(acc1[r]);
            }
        } else {
            unsigned short* dst = (p == 1) ? Kp : Qp;
            float sc = (p == 2) ? QSC : 1.0f;
            unsigned short* db = dst + (((size_t)(n * HEADS + h)) * LSEQ + l0 + w * 32) * HD;
            #pragma unroll
            for (int r = 0; r < 16; ++r) {
                int tok = (r & 3) + 8 * (r >> 2) + 4 * hi;
                db[(size_t)tok * HD + l5]      = bf16r(acc0[r] * sc);
                db[(size_t)tok * HD + 32 + l5] = bf16r(acc1[r] * sc);
            }
        }
    }
}

// ---------------------------------------------------------------------------
// Kernel 2: MFMA flash attention, S^T orientation (unchanged from R5).
// ---------------------------------------------------------------------------
__global__ __launch_bounds__(256, 3) void attn_kernel(
    const unsigned short* __restrict__ Qp, const unsigned short* __restrict__ Kp,
    const unsigned short* __restrict__ Vt,
    unsigned short* __restrict__ AOh, unsigned short* __restrict__ AOl)
{
    __shared__ uint4 sK[128 * 8];    // 16KB
    __shared__ uint4 sV[64 * 16];    // 16KB
    __shared__ uint4 sP4[4 * 128];   //  8KB

    const int t = threadIdx.x;
    const int lane = t & 63, w = t >> 6;
    const int l5 = lane & 31, hi = lane >> 5;
    const int n = blockIdx.z, h = blockIdx.y;
    const int q0 = blockIdx.x * 128;
    const size_t hoff = ((size_t)n * HEADS + h) * (size_t)(LSEQ * HD);
    const unsigned short* Kh = Kp + hoff;
    const unsigned short* Vh = Vt + hoff;

    bf16x8 qf[4];
    {
        const uint4* qg = (const uint4*)(Qp + hoff + (size_t)(q0 + w * 32 + l5) * HD);
        #pragma unroll
        for (int kc = 0; kc < 4; ++kc) qf[kc] = as_bf16x8(qg[kc * 2 + hi]);
    }

    f32x16 Oa0, Oa1;
    #pragma unroll
    for (int i = 0; i < 16; ++i) { Oa0[i] = 0.f; Oa1[i] = 0.f; }
    float lsum = 0.f;

    uint2*       sPw = (uint2*)(sP4 + w * 128);
    const uint4* sPq = sP4 + w * 128;
    const int    psw = (l5 >> 1) & 3;

    for (int kt = 0; kt < LSEQ; kt += 128) {
        const uint4* gK = (const uint4*)(Kh + (size_t)kt * HD);
        #pragma unroll
        for (int i = 0; i < 4; ++i) {
            int u = t + 256 * i; int key = u >> 3, gd = u & 7;
            sK[key * 8 + (gd ^ (key & 7))] = gK[u];
        }
        #pragma unroll
        for (int i = 0; i < 4; ++i) {
            int u = t + 256 * i; int d = u >> 4, kg = u & 15;
            sV[d * 16 + (kg ^ (d & 7))] = *(const uint4*)(Vh + (size_t)d * LSEQ + kt + kg * 8);
        }
        __syncthreads();

        #pragma unroll
        for (int tc = 0; tc < 4; ++tc) {
            f32x16 c;
            #pragma unroll
            for (int i = 0; i < 16; ++i) c[i] = 0.f;
            int key = tc * 32 + l5;
            #pragma unroll
            for (int kc = 0; kc < 4; ++kc) {
                bf16x8 kf = as_bf16x8(sK[key * 8 + ((kc * 2 + hi) ^ (l5 & 7))]);
                c = __builtin_amdgcn_mfma_f32_32x32x16_bf16(kf, qf[kc], c, 0, 0, 0);
            }

            #pragma unroll
            for (int g = 0; g < 4; ++g) {
                float p0 = exp2f(c[4 * g]);
                float p1 = exp2f(c[4 * g + 1]);
                float p2 = exp2f(c[4 * g + 2]);
                float p3 = exp2f(c[4 * g + 3]);
                uint2 pk;
                pk.x = __builtin_amdgcn_perm(__float_as_uint(p1), __float_as_uint(p0), 0x07060302u);
                pk.y = __builtin_amdgcn_perm(__float_as_uint(p3), __float_as_uint(p2), 0x07060302u);
                lsum += (__uint_as_float(__float_as_uint(p0) & 0xffff0000u)
                       + __uint_as_float(__float_as_uint(p1) & 0xffff0000u))
                      + (__uint_as_float(__float_as_uint(p2) & 0xffff0000u)
                       + __uint_as_float(__float_as_uint(p3) & 0xffff0000u));
                sPw[l5 * 8 + ((g ^ psw) << 1) + hi] = pk;
            }

            #pragma unroll
            for (int win = 0; win < 2; ++win) {
                bf16x8 pf = as_bf16x8(sPq[l5 * 4 + (((win << 1) + hi) ^ psw)]);
                int vg = tc * 4 + (win << 1) + hi;
                bf16x8 v0 = as_bf16x8(sV[ l5       * 16 + (vg ^ (l5 & 7))]);
                Oa0 = __builtin_amdgcn_mfma_f32_32x32x16_bf16(pf, v0, Oa0, 0, 0, 0);
                bf16x8 v1 = as_bf16x8(sV[(32 + l5) * 16 + (vg ^ (l5 & 7))]);
                Oa1 = __builtin_amdgcn_mfma_f32_32x32x16_bf16(pf, v1, Oa1, 0, 0, 0);
            }
        }
        __syncthreads();
    }

    lsum += __shfl_xor(lsum, 32);
    float inv = 1.0f / lsum;
    float* sLf = (float*)sK;
    if (hi == 0) sLf[w * 32 + l5] = inv;

    unsigned short* hB = AOh + hoff;
    unsigned short* lB = AOl + hoff;
    #pragma unroll
    for (int r = 0; r < 16; ++r) {
        int qr = (r & 3) + 8 * (r >> 2) + 4 * hi;
        float invq = sLf[w * 32 + qr];
        size_t row = (size_t)(q0 + w * 32 + qr) * HD;
        float o0 = Oa0[r] * invq;
        float o1 = Oa1[r] * invq;
        unsigned short h0 = bf16r(o0), h1 = bf16r(o1);
        hB[row +      l5] = h0;
        hB[row + 32 + l5] = h1;
        lB[row +      l5] = bf16r(o0 - bfh2f(h0));
        lB[row + 32 + l5] = bf16r(o1 - bfh2f(h1));
    }
}

// ---------------------------------------------------------------------------
// Kernel 2.5: split Wo into bf16 hi/lo (unchanged).
// ---------------------------------------------------------------------------
__global__ __launch_bounds__(256) void wsplit_kernel(
    const float* __restrict__ Wo,
    unsigned short* __restrict__ Woh, unsigned short* __restrict__ Wol)
{
    int i = blockIdx.x * 256 + threadIdx.x;
    float4 v = ((const float4*)Wo)[i];
    ushort4 h, l;
    h.x = bf16r(v.x); l.x = bf16r(v.x - bfh2f(h.x));
    h.y = bf16r(v.y); l.y = bf16r(v.y - bfh2f(h.y));
    h.z = bf16r(v.z); l.z = bf16r(v.z - bfh2f(h.z));
    h.w = bf16r(v.w); l.w = bf16r(v.w - bfh2f(h.w));
    ((ushort4*)Woh)[i] = h;
    ((ushort4*)Wol)[i] = l;
}

// ---------------------------------------------------------------------------
// Kernel 3: output projection, split-bf16 MFMA GEMM (unchanged).
// ---------------------------------------------------------------------------
__global__ __launch_bounds__(256, 2) void outproj_kernel(
    const unsigned short* __restrict__ AOh, const unsigned short* __restrict__ AOl,
    const unsigned short* __restrict__ Woh, const unsigned short* __restrict__ Wol,
    const float* __restrict__ bo, float* __restrict__ out)
{
    __shared__ uint4 sAh[1024];
    __shared__ uint4 sAl[1024];
    __shared__ uint4 sBh[1024];
    __shared__ uint4 sBl[1024];

    const int t = threadIdx.x;
    const int lane = t & 63, w = t >> 6;
    const int l5 = lane & 31, hi = lane >> 5;
    const int m0 = blockIdx.x * 128;
    const int e0 = blockIdx.y * 128;
    const int n  = m0 >> 11, l0 = m0 & 2047;
    const int mr = (w & 1) * 64, nc = (w >> 1) * 64;

    f32x16 acc[2][2];
    #pragma unroll
    for (int a = 0; a < 2; ++a)
        #pragma unroll
        for (int b = 0; b < 2; ++b)
            #pragma unroll
            for (int i = 0; i < 16; ++i) acc[a][b][i] = 0.f;

    for (int hh = 0; hh < 16; ++hh) {
        const unsigned short* Ah = AOh + ((((size_t)n * HEADS + hh) * LSEQ) + l0) * HD;
        const unsigned short* Al = AOl + ((((size_t)n * HEADS + hh) * LSEQ) + l0) * HD;
        #pragma unroll
        for (int i = 0; i < 4; ++i) {
            int g = t + i * 256;
            gload_lds16(Ah + g * 8, sAh + g);
            gload_lds16(Al + g * 8, sAl + g);
            int e = g >> 3, gf = g & 7;
            size_t boff = (size_t)(e0 + e) * EMBED + hh * 64 + gf * 8;
            gload_lds16(Woh + boff, sBh + g);
            gload_lds16(Wol + boff, sBl + g);
        }
        __syncthreads();

        #pragma unroll
        for (int s = 0; s < 4; ++s) {
            int gcol = s * 2 + hi;
            bf16x8 ah0 = as_bf16x8(sAh[(mr +      l5) * 8 + gcol]);
            bf16x8 ah1 = as_bf16x8(sAh[(mr + 32 + l5) * 8 + gcol]);
            bf16x8 al0 = as_bf16x8(sAl[(mr +      l5) * 8 + gcol]);
            bf16x8 al1 = as_bf16x8(sAl[(mr + 32 + l5) * 8 + gcol]);
            bf16x8 bh0 = as_bf16x8(sBh[(nc +      l5) * 8 + gcol]);
            bf16x8 bh1 = as_bf16x8(sBh[(nc + 32 + l5) * 8 + gcol]);
            bf16x8 bl0 = as_bf16x8(sBl[(nc +      l5) * 8 + gcol]);
            bf16x8 bl1 = as_bf16x8(sBl[(nc + 32 + l5) * 8 + gcol]);

            acc[0][0] = __builtin_amdgcn_mfma_f32_32x32x16_bf16(ah0, bh0, acc[0][0], 0, 0, 0);
            acc[0][1] = __builtin_amdgcn_mfma_f32_32x32x16_bf16(ah0, bh1, acc[0][1], 0, 0, 0);
            acc[1][0] = __builtin_amdgcn_mfma_f32_32x32x16_bf16(ah1, bh0, acc[1][0], 0, 0, 0);
            acc[1][1] = __builtin_amdgcn_mfma_f32_32x32x16_bf16(ah1, bh1, acc[1][1], 0, 0, 0);

            acc[0][0] = __builtin_amdgcn_mfma_f32_32x32x16_bf16(ah0, bl0, acc[0][0], 0, 0, 0);
            acc[0][1] = __builtin_amdgcn_mfma_f32_32x32x16_bf16(ah0, bl1, acc[0][1], 0, 0, 0);
            acc[1][0] = __builtin_amdgcn_mfma_f32_32x32x16_bf16(ah1, bl0, acc[1][0], 0, 0, 0);
            acc[1][1] = __builtin_amdgcn_mfma_f32_32x32x16_bf16(ah1, bl1, acc[1][1], 0, 0, 0);

            acc[0][0] = __builtin_amdgcn_mfma_f32_32x32x16_bf16(al0, bh0, acc[0][0], 0, 0, 0);
            acc[0][1] = __builtin_amdgcn_mfma_f32_32x32x16_bf16(al0, bh1, acc[0][1], 0, 0, 0);
            acc[1][0] = __builtin_amdgcn_mfma_f32_32x32x16_bf16(al1, bh0, acc[1][0], 0, 0, 0);
            acc[1][1] = __builtin_amdgcn_mfma_f32_32x32x16_bf16(al1, bh1, acc[1][1], 0, 0, 0);
        }
        __syncthreads();
    }

    float b0 = bo[e0 + nc + l5];
    float b1 = bo[e0 + nc + 32 + l5];
    #pragma unroll
    for (int ti = 0; ti < 2; ++ti) {
        #pragma unroll
        for (int r = 0; r < 16; ++r) {
            int row = m0 + mr + ti * 32 + (r & 3) + 8 * (r >> 2) + 4 * hi;
            float* o = out + (size_t)row * EMBED + e0 + nc;
            o[l5]      = acc[ti][0][r] + b0;
            o[32 + l5] = acc[ti][1][r] + b1;
        }
    }
}

// ---------------------------------------------------------------------------
extern "C" void kernel_launch(void* const* d_in, const int* in_sizes, int n_in,
                              void* d_out, int out_size, void* d_ws, size_t ws_size,
                              hipStream_t stream)
{
    const float* values  = (const float*)d_in[0];
    const float* keys    = (const float*)d_in[1];
    const float* queries = (const float*)d_in[2];
    const float* Wv      = (const float*)d_in[3];
    const float* Wk      = (const float*)d_in[4];
    const float* Wq      = (const float*)d_in[5];
    const float* Wo      = (const float*)d_in[6];
    const float* bo      = (const float*)d_in[7];
    float* out = (float*)d_out;

    const size_t bufElems = (size_t)NB * HEADS * LSEQ * HD;   // 8,388,608
    unsigned short* Qp  = (unsigned short*)d_ws;
    unsigned short* Kp  = Qp  + bufElems;
    unsigned short* Vt  = Kp  + bufElems;
    unsigned short* AOh = Vt  + bufElems;
    unsigned short* AOl = AOh + bufElems;
    unsigned short* Woh = AOl + bufElems;
    unsigned short* Wol = Woh + (size_t)EMBED * EMBED;

    wsplit_kernel<<<dim3(1024), 256, 0, stream>>>(Wo, Woh, Wol);
    proj_kernel<<<dim3(NB * 16, HEADS), 256, 0, stream>>>(values, keys, queries, Wv, Wk, Wq, Vt, Kp, Qp);
    attn_kernel<<<dim3(LSEQ / 128, HEADS, NB), 256, 0, stream>>>(Qp, Kp, Vt, AOh, AOl);
    outproj_kernel<<<dim3(NB * LSEQ / 128, EMBED / 128), 256, 0, stream>>>(AOh, AOl, Woh, Wol, bo, out);
}